// Round 1
// baseline (102.800 us; speedup 1.0000x reference)
//
#include <hip/hip_runtime.h>

// Problem: y[32,8192] = x[32,8192] @ (A[8192,64] @ B[64,8192])^T + bias[8192]
// Factored: t[32,64] = x @ B^T ; y = t @ A^T + bias
// All fp32. ~67 MFLOP, ~6 MB traffic.

#define BATCH 32
#define INF   8192
#define OUTF  8192
#define RANK  64

// ---------------- Kernel 1: t = x @ B^T, K-split with atomics ----------------
// Grid: 256 blocks, one K-chunk of 32 each. Block: 128 threads (2 waves).
// LDS: x-chunk [32][8 float4], B-chunk [64][8 float4], XOR-swizzled so that
// compute-phase ds_read_b128 is conflict-free (bank group = (kk ^ row>>2)*4,
// broadcast across the 8 lanes sharing a row).
__global__ __launch_bounds__(128) void lr_k1(const float* __restrict__ x,
                                             const float* __restrict__ B,
                                             float* __restrict__ t) {
    const int c   = blockIdx.x;      // K-chunk index, K-offset = c*32 floats = c*8 float4
    const int tid = threadIdx.x;

    __shared__ float4 xs[BATCH * 8];  // [row=b][kk4] swizzled
    __shared__ float4 bs[RANK * 8];   // [row=r][kk4] swizzled

    const float4* x4 = (const float4*)x;  // row stride 2048 float4
    const float4* b4 = (const float4*)B;  // row stride 2048 float4

    // Stage x chunk: 32*8 = 256 float4, 2 per thread. Coalesced global reads.
#pragma unroll
    for (int it = 0; it < 2; ++it) {
        int gi  = tid + it * 128;
        int row = gi >> 3, kk = gi & 7;
        xs[row * 8 + (kk ^ ((row >> 2) & 7))] = x4[row * 2048 + c * 8 + kk];
    }
    // Stage B chunk: 64*8 = 512 float4, 4 per thread.
#pragma unroll
    for (int it = 0; it < 4; ++it) {
        int gi  = tid + it * 128;
        int row = gi >> 3, kk = gi & 7;
        bs[row * 8 + (kk ^ ((row >> 2) & 7))] = b4[row * 2048 + c * 8 + kk];
    }
    __syncthreads();

    // 4b x 4r register tile per thread: 8 tb x 16 tr = 128 threads covers 32x64.
    const int tb = tid & 7;        // b0 = tb*4
    const int tr = tid >> 3;       // r0 = tr*4
    const int b0 = tb * 4, r0 = tr * 4;

    float acc[4][4] = {};
#pragma unroll
    for (int kk = 0; kk < 8; ++kk) {
        float4 xa[4], bb[4];
#pragma unroll
        for (int j = 0; j < 4; ++j) xa[j] = xs[(b0 + j) * 8 + (kk ^ (tb & 7))];
#pragma unroll
        for (int j = 0; j < 4; ++j) bb[j] = bs[(r0 + j) * 8 + (kk ^ (tr & 7))];
#pragma unroll
        for (int i = 0; i < 4; ++i)
#pragma unroll
            for (int j = 0; j < 4; ++j) {
                acc[i][j] += xa[i].x * bb[j].x;
                acc[i][j] += xa[i].y * bb[j].y;
                acc[i][j] += xa[i].z * bb[j].z;
                acc[i][j] += xa[i].w * bb[j].w;
            }
    }

#pragma unroll
    for (int i = 0; i < 4; ++i)
#pragma unroll
        for (int j = 0; j < 4; ++j)
            atomicAdd(&t[(b0 + i) * RANK + (r0 + j)], acc[i][j]);
}

// ---------------- Kernel 2: y = t @ A^T + bias ----------------
// Grid: 32 o-blocks x 8 b-blocks = 256 blocks x 256 threads.
// Thread owns one output column o and 4 batches. A-row (64 floats) in regs,
// t read with wave-uniform indices -> scalar loads.
__global__ __launch_bounds__(256) void lr_k2(const float* __restrict__ A,
                                             const float* __restrict__ t,
                                             const float* __restrict__ bias,
                                             float* __restrict__ y) {
    const int o  = (blockIdx.x & 31) * 256 + threadIdx.x;
    const int b0 = (blockIdx.x >> 5) * 4;

    const float4* A4 = (const float4*)A;   // A[o][r] -> A4[o*16 + r4]
    const float4* t4 = (const float4*)t;   // t[b][r] -> t4[b*16 + r4]

    float4 a[16];
#pragma unroll
    for (int r4 = 0; r4 < 16; ++r4) a[r4] = A4[o * 16 + r4];

    const float bv = bias[o];

#pragma unroll
    for (int jb = 0; jb < 4; ++jb) {
        float acc = bv;
#pragma unroll
        for (int r4 = 0; r4 < 16; ++r4) {
            float4 tv = t4[(b0 + jb) * 16 + r4];  // wave-uniform -> s_load
            acc += a[r4].x * tv.x + a[r4].y * tv.y + a[r4].z * tv.z + a[r4].w * tv.w;
        }
        y[(b0 + jb) * OUTF + o] = acc;
    }
}

extern "C" void kernel_launch(void* const* d_in, const int* in_sizes, int n_in,
                              void* d_out, int out_size, void* d_ws, size_t ws_size,
                              hipStream_t stream) {
    const float* x    = (const float*)d_in[0];   // [32, 8192]
    const float* A    = (const float*)d_in[1];   // [8192, 64]
    const float* B    = (const float*)d_in[2];   // [64, 8192]
    const float* bias = (const float*)d_in[3];   // [8192]
    float*       y    = (float*)d_out;           // [32, 8192]
    float*       t    = (float*)d_ws;            // [32, 64] scratch

    hipMemsetAsync(t, 0, BATCH * RANK * sizeof(float), stream);
    lr_k1<<<256, 128, 0, stream>>>(x, B, t);
    lr_k2<<<256, 256, 0, stream>>>(A, t, bias, y);
}

// Round 2
// 75.575 us; speedup vs baseline: 1.3602x; 1.3602x over previous
//
#include <hip/hip_runtime.h>

// y[32,8192] = x[32,8192] @ (A[8192,64] @ B[64,8192])^T + bias
// Factored: t = x @ B^T [32,64]; y = t @ A^T + bias.
// k1: split-K partials (no atomics, no memset) -> ws
// k2: per-block partial reduction + LDS-staged A, coalesced everything.

#define BATCH 32
#define INF   8192
#define OUTF  8192
#define RANK  64
#define KCH   128            // number of K chunks / k1 blocks
// chunk = 8192/128 = 64 floats = 16 float4

// ---------------- k1: part[c][32][64] = x[:,chunk_c] @ B[:,chunk_c]^T ----------
__global__ __launch_bounds__(256) void lr_k1(const float* __restrict__ x,
                                             const float* __restrict__ B,
                                             float* __restrict__ part) {
    const int c   = blockIdx.x;
    const int tid = threadIdx.x;

    __shared__ float4 xs[BATCH * 16];  // row-major, kk XOR-swizzled
    __shared__ float4 bs[RANK * 16];

    const float4* x4 = (const float4*)x;  // row stride 2048 f4
    const float4* b4 = (const float4*)B;

    // Stage x chunk: 512 f4, 2/thread. Global: 16 consecutive lanes read 16
    // consecutive f4 (256B segments). LDS write: permutation within a row -> no conflict.
#pragma unroll
    for (int it = 0; it < 2; ++it) {
        int gi = tid + it * 256, row = gi >> 4, kk = gi & 15;
        xs[row * 16 + (kk ^ (row & 15))] = x4[row * 2048 + c * 16 + kk];
    }
    // Stage B chunk: 1024 f4, 4/thread.
#pragma unroll
    for (int it = 0; it < 4; ++it) {
        int gi = tid + it * 256, row = gi >> 4, kk = gi & 15;
        bs[row * 16 + (kk ^ (row & 15))] = b4[row * 2048 + c * 16 + kk];
    }
    __syncthreads();

    // Thread tile: 2 batches x 4 ranks (ranks strided by 16 so per-instr lane
    // addresses land in distinct/2-way bank groups).
    const int bq = tid >> 4;   // b rows: bq*2, bq*2+1
    const int rr = tid & 15;   // r cols: rr + 16j

    float acc[2][4] = {};
#pragma unroll
    for (int kk = 0; kk < 16; ++kk) {
        float4 xa[2], bb[4];
#pragma unroll
        for (int i = 0; i < 2; ++i) {
            int row = bq * 2 + i;
            xa[i] = xs[row * 16 + (kk ^ (row & 15))];   // 4 distinct rows/wave -> 4 groups, free
        }
#pragma unroll
        for (int j = 0; j < 4; ++j) {
            int r = rr + 16 * j;
            bb[j] = bs[r * 16 + (kk ^ (r & 15))];       // 16 rows -> 8 groups x 2 = 2-way, free
        }
#pragma unroll
        for (int i = 0; i < 2; ++i)
#pragma unroll
            for (int j = 0; j < 4; ++j)
                acc[i][j] += xa[i].x * bb[j].x + xa[i].y * bb[j].y +
                             xa[i].z * bb[j].z + xa[i].w * bb[j].w;
    }

    // part[c][b][r], scalar stores: 16 consecutive lanes -> 64B contiguous.
#pragma unroll
    for (int i = 0; i < 2; ++i)
#pragma unroll
        for (int j = 0; j < 4; ++j)
            part[c * 2048 + (bq * 2 + i) * 64 + 16 * j + rr] = acc[i][j];
}

// ---------------- k2: y = reduce(part) @ A^T + bias ----------------
// Grid: 32 o-groups x 8 b-groups = 256 blocks x 256 threads.
// Block: outputs og*256..+255, batches b0..b0+3.
__global__ __launch_bounds__(256) void lr_k2(const float* __restrict__ A,
                                             const float* __restrict__ part,
                                             const float* __restrict__ bias,
                                             float* __restrict__ y) {
    const int og  = blockIdx.x >> 3;       // 0..31
    const int b0  = (blockIdx.x & 7) * 4;  // 0..28
    const int tid = threadIdx.x;

    __shared__ float4 as[256 * 16];  // 64 KB A tile, XOR-swizzled
    __shared__ float  ts[4 * 64];    // reduced t rows b0..b0+3

    // Reduce partials: element e=tid of the block's 4x64 slice, sum over 128 chunks.
    // Per-c loads: 256 lanes read 1KB contiguous (coalesced, L2-resident).
    {
        float s = 0.f;
#pragma unroll 8
        for (int c = 0; c < KCH; ++c) s += part[c * 2048 + b0 * 64 + tid];
        ts[tid] = s;
    }

    // Stage A tile: A4[(og*256+ol)*16 + r4] is 4096 consecutive f4 -> perfectly
    // coalesced. Swizzled store is a permutation within each 256B row -> no conflict.
    const float4* A4 = (const float4*)A;
#pragma unroll
    for (int it = 0; it < 16; ++it) {
        int gi = tid + it * 256, ol = gi >> 4, r4 = gi & 15;
        as[ol * 16 + (r4 ^ (ol & 15))] = A4[(og * 256 + ol) * 16 + r4];
    }
    __syncthreads();

    const int o = og * 256 + tid;
    const float bv = bias[o];
    float accv[4] = {bv, bv, bv, bv};

    const float4* t4 = (const float4*)ts;
#pragma unroll
    for (int r4 = 0; r4 < 16; ++r4) {
        float4 a = as[tid * 16 + (r4 ^ (tid & 15))];  // 8 groups x 8 -> mild conflict
#pragma unroll
        for (int jb = 0; jb < 4; ++jb) {
            float4 tv = t4[jb * 16 + r4];             // wave-uniform -> broadcast, free
            accv[jb] += a.x * tv.x + a.y * tv.y + a.z * tv.z + a.w * tv.w;
        }
    }

#pragma unroll
    for (int jb = 0; jb < 4; ++jb)
        y[(b0 + jb) * OUTF + o] = accv[jb];           // coalesced
}

extern "C" void kernel_launch(void* const* d_in, const int* in_sizes, int n_in,
                              void* d_out, int out_size, void* d_ws, size_t ws_size,
                              hipStream_t stream) {
    const float* x    = (const float*)d_in[0];   // [32, 8192]
    const float* A    = (const float*)d_in[1];   // [8192, 64]
    const float* B    = (const float*)d_in[2];   // [64, 8192]
    const float* bias = (const float*)d_in[3];   // [8192]
    float*       y    = (float*)d_out;           // [32, 8192]
    float*       part = (float*)d_ws;            // [128][32][64] partials (1 MB)

    lr_k1<<<KCH, 256, 0, stream>>>(x, B, part);
    lr_k2<<<256, 256, 0, stream>>>(A, part, bias, y);
}